// Round 4
// baseline (284.351 us; speedup 1.0000x reference)
//
#include <hip/hip_runtime.h>
#include <hip/hip_bf16.h>
#include <math.h>

// Problem constants
#define B_   2
#define T_   2048
#define D_   2048
#define NH_  16
#define NKV_ 4
#define HD_  128
#define MROWS (B_*T_)          // 4096
#define NQKV  (NH_*HD_ + 2*NKV_*HD_)  // 3072

typedef __bf16 bf16_t;
typedef __bf16 bf16x8 __attribute__((ext_vector_type(8)));
typedef __bf16 bf16x4 __attribute__((ext_vector_type(4)));
typedef float  floatx4 __attribute__((ext_vector_type(4)));

// ---------------------------------------------------------------------------
// async global->LDS, 16B per lane. LDS dest must be wave-uniform base + lane*16.
__device__ __forceinline__ void async_copy16(const bf16_t* gsrc, bf16_t* ldst) {
  __builtin_amdgcn_global_load_lds(
      (const __attribute__((address_space(1))) unsigned int*)gsrc,
      (__attribute__((address_space(3))) unsigned int*)ldst, 16, 0, 0);
}

// ---------------------------------------------------------------------------
// Fused prep: z=0..3 -> transpose+cast weight z; z=4 -> elementwise cast of x.
// grid (64, 64, 5), block (32,8)
__global__ void prep_fused(const float* __restrict__ s0, const float* __restrict__ s1,
                           const float* __restrict__ s2, const float* __restrict__ s3,
                           const float* __restrict__ sx,
                           bf16_t* __restrict__ d0, bf16_t* __restrict__ d1,
                           bf16_t* __restrict__ d2, bf16_t* __restrict__ d3,
                           bf16_t* __restrict__ dx) {
  const int z = blockIdx.z;
  const int tx = threadIdx.x, ty = threadIdx.y;
  if (z == 4) {
    int i = ((blockIdx.y * 64 + blockIdx.x) * 256 + ty * 32 + tx) * 8;
    float4 a = *(const float4*)(sx + i);
    float4 b = *(const float4*)(sx + i + 4);
    bf16x8 v;
    v[0]=(bf16_t)a.x; v[1]=(bf16_t)a.y; v[2]=(bf16_t)a.z; v[3]=(bf16_t)a.w;
    v[4]=(bf16_t)b.x; v[5]=(bf16_t)b.y; v[6]=(bf16_t)b.z; v[7]=(bf16_t)b.w;
    *(bf16x8*)(dx + i) = v;
    return;
  }
  const int N = (z == 1 || z == 2) ? 512 : 2048;
  const int n0 = blockIdx.x * 32;
  if (n0 >= N) return;
  const float* src = (z == 0) ? s0 : (z == 1) ? s1 : (z == 2) ? s2 : s3;
  bf16_t*      dst = (z == 0) ? d0 : (z == 1) ? d1 : (z == 2) ? d2 : d3;
  const int K = 2048;
  __shared__ float tile[32][33];
  int k0 = blockIdx.y * 32;
#pragma unroll
  for (int r = 0; r < 4; r++)
    tile[ty + r*8][tx] = src[(size_t)(k0 + ty + r*8) * N + n0 + tx];
  __syncthreads();
#pragma unroll
  for (int r = 0; r < 4; r++)
    dst[(size_t)(n0 + ty + r*8) * K + k0 + tx] = (bf16_t)tile[tx][ty + r*8];
}

// ---------------------------------------------------------------------------
// C(M,N) = A(M,K) * Bt(N,K)^T   all bf16 in, OUT_T out.
// 128x128 tile, BK=64, 4 waves (2x2 of 64x64), 16x16x32 MFMA.
template <typename OUT_T>
__global__ __launch_bounds__(256, 3)
void gemm_bt(const bf16_t* __restrict__ A, const bf16_t* __restrict__ Bt,
             OUT_T* __restrict__ C, int M, int N, int K) {
  __shared__ __align__(16) bf16_t As[128 * 64];
  __shared__ __align__(16) bf16_t Bs[128 * 64];
  const int tid  = threadIdx.x;
  const int wave = tid >> 6, lane = tid & 63;
  const int quad = lane >> 4, l16 = lane & 15;
  const int nBlocksM = M >> 7;
  const int bm = blockIdx.x % nBlocksM, bn = blockIdx.x / nBlocksM;
  const int m0 = bm * 128, n0 = bn * 128;
  const int wm = (wave >> 1) * 64, wn = (wave & 1) * 64;

  floatx4 acc[4][4];
#pragma unroll
  for (int i = 0; i < 4; i++)
#pragma unroll
    for (int j = 0; j < 4; j++) acc[i][j] = floatx4{0.f, 0.f, 0.f, 0.f};

  for (int k0 = 0; k0 < K; k0 += 64) {
    __syncthreads();
#pragma unroll
    for (int i = 0; i < 4; i++) {
      int e = i * 256 + tid;
      int row = e >> 3, grp = e & 7;
      int gg = grp ^ (row & 7);
      async_copy16(A + (size_t)(m0 + row) * K + k0 + gg * 8, As + e * 8);
    }
#pragma unroll
    for (int i = 0; i < 4; i++) {
      int e = i * 256 + tid;
      int row = e >> 3, grp = e & 7;
      int gg = grp ^ (row & 7);
      async_copy16(Bt + (size_t)(n0 + row) * K + k0 + gg * 8, Bs + e * 8);
    }
    __syncthreads();
#pragma unroll
    for (int ks = 0; ks < 2; ks++) {
      bf16x8 af[4], bfr[4];
      int grp = ks * 4 + quad;
#pragma unroll
      for (int mi = 0; mi < 4; mi++) {
        int row = wm + mi * 16 + l16;
        af[mi] = *(const bf16x8*)(As + row * 64 + ((grp ^ (row & 7)) << 3));
      }
#pragma unroll
      for (int ni = 0; ni < 4; ni++) {
        int row = wn + ni * 16 + l16;
        bfr[ni] = *(const bf16x8*)(Bs + row * 64 + ((grp ^ (row & 7)) << 3));
      }
#pragma unroll
      for (int mi = 0; mi < 4; mi++)
#pragma unroll
        for (int ni = 0; ni < 4; ni++)
          acc[mi][ni] = __builtin_amdgcn_mfma_f32_16x16x32_bf16(af[mi], bfr[ni], acc[mi][ni], 0, 0, 0);
    }
  }
#pragma unroll
  for (int mi = 0; mi < 4; mi++) {
#pragma unroll
    for (int r = 0; r < 4; r++) {
      int row = m0 + wm + mi * 16 + quad * 4 + r;
      size_t base = (size_t)row * N + n0 + wn;
#pragma unroll
      for (int ni = 0; ni < 4; ni++)
        C[base + ni * 16 + l16] = (OUT_T)acc[mi][ni][r];
    }
  }
}

// ---------------------------------------------------------------------------
// Fused K-RoPE + V-transpose (one dispatch; branch is block-uniform).
// V is written INTERLEAVED in global: within each 64-key tile, key
// k = 16ks+4q+32hi+r (ks<2,q<4,hi<2,r<4) is stored at pos = ((ks*4+q)<<3)|(hi<<2)|r.
// So each 16B granule G=ks*4+q of a d-row holds keys [16ks+4q+0..3 | +32..35] —
// exactly the register-P PV fragment order; flash stages it with plain copy16.
#define ROPE_BLOCKS ((MROWS * NKV_ * 64) / 256)   // 4096
__global__ void kv_prep(const bf16_t* __restrict__ qkv, bf16_t* __restrict__ Kb,
                        bf16_t* __restrict__ Vt) {
  if (blockIdx.x < ROPE_BLOCKS) {
    int g = blockIdx.x * 256 + threadIdx.x;
    int j = g & 63;
    int rest = g >> 6;
    int kvh = rest & 3;
    int row = rest >> 2;                // b*T + t
    int t = row & (T_ - 1);
    int b = row >> 11;                  // T_ = 2048
    const bf16_t* src = qkv + (size_t)row * NQKV + NH_ * HD_ + kvh * HD_;
    float ang = (float)t * __expf(-0.14391156816f * (float)j);
    float sn, cs;
    __sincosf(ang, &sn, &cs);
    float x0 = (float)src[j];
    float x1 = (float)src[j + 64];
    bf16_t* dst = Kb + ((size_t)(b * NKV_ + kvh) * T_ + t) * HD_;
    dst[j]      = (bf16_t)(x0 * cs - x1 * sn);
    dst[j + 64] = (bf16_t)(x1 * cs + x0 * sn);
    return;
  }
  __shared__ float tile[32][33];
  int bb = blockIdx.x - ROPE_BLOCKS;          // [0, 2048)
  int bx = bb & 63, by = (bb >> 6) & 3, bz = bb >> 8;
  int t0 = bx * 32, d0 = by * 32;
  int b = bz / NKV_, kvh = bz % NKV_;
  int tx = threadIdx.x & 31, ty = threadIdx.x >> 5;
#pragma unroll
  for (int r = 0; r < 4; r++) {
    int t = t0 + ty + r * 8;
    tile[ty + r*8][tx] =
        (float)qkv[(size_t)(b * T_ + t) * NQKV + (NH_ + NKV_) * HD_ + kvh * HD_ + d0 + tx];
  }
  __syncthreads();
#pragma unroll
  for (int r = 0; r < 4; r++) {
    int d = d0 + ty + r * 8;
    int t = t0 + tx;
    int k = t & 63;
    int pos = ((((k >> 4) & 1) * 4 + ((k >> 2) & 3)) << 3) + ((k >> 5) << 2) + (k & 3);
    Vt[((size_t)(b * NKV_ + kvh) * HD_ + d) * T_ + (t & ~63) + pos] =
        (bf16_t)tile[tx][ty + r*8];
  }
}

// ---------------------------------------------------------------------------
// Flash attention v7: 128 q-rows/block (two 64-row groups), register-P PV,
// interleaved-V global layout (staged with copy16, conflict-free b128 reads).
//
// Per staged 64-key tile: 32 QK MFMA share 16 K-fragment LDS reads, 32 PV MFMA
// share 16 V-fragment reads — 2x compute per barrier/stage vs v6, halved
// LDS-read:MFMA ratio. The final tile's g=0 slice is fully masked (-1e30 ->
// exp2 -> 0) instead of branched out; ~3% waste, zero divergence.
//
// Load balance: 512 blocks = exactly 2/CU (64KB LDS). Blocks bid and bid+256
// land on the same CU under plain AND XCD round-robin; mapping qtp<8 ->
// qt2=15-qtp else qtp-8 pairs them so every CU's pair does 34 k-tiles.
//
// + T13 defer-max + T5 s_setprio (unchanged).
__global__ __launch_bounds__(256, 2)
void flash_attn(const bf16_t* __restrict__ qkv, const bf16_t* __restrict__ Kb,
                const bf16_t* __restrict__ Vt, bf16_t* __restrict__ Ob) {
  __shared__ __align__(16) bf16_t Ks[2][64 * 128];   // (key, d), swizzle grp^(row&15)
  __shared__ __align__(16) bf16_t Vs[2][128 * 64];   // (d, key-interleaved), swz grp^(row&7)

  const int tid = threadIdx.x;
  const int wave = tid >> 6, lane = tid & 63;
  const int quad = lane >> 4, l16 = lane & 15;
  const int bid = blockIdx.x;
  const int bh = bid & 31;                    // (b,h)
  const int qtp = bid >> 5;                   // 0..15
  const int qt2 = (qtp < 8) ? (15 - qtp) : (qtp - 8);  // paired load-balance map
  const int h = bh & 15;
  const int b = bh >> 4;
  const int kv = h >> 2;                      // GQA: n_rep = 4
  const int q0 = qt2 * 128;
  const int ktLast = 2 * qt2 + 1;

  const bf16_t* kbase = Kb + ((size_t)(b * NKV_ + kv) * T_) * HD_;
  const bf16_t* vbase = Vt + ((size_t)(b * NKV_ + kv) * HD_) * T_;

  auto stage = [&](int kt, int bufi) {
#pragma unroll
    for (int i = 0; i < 4; i++) {
      int e = i * 256 + tid;
      int row = e >> 4, grp = e & 15;
      int gg = grp ^ (row & 15);
      async_copy16(kbase + (size_t)(kt * 64 + row) * HD_ + gg * 8, &Ks[bufi][e * 8]);
    }
#pragma unroll
    for (int i = 0; i < 4; i++) {
      int e = i * 256 + tid;
      int row = e >> 3, grp = e & 7;
      int gg = grp ^ (row & 7);
      async_copy16(vbase + (size_t)row * T_ + kt * 64 + gg * 8, &Vs[bufi][e * 8]);
    }
  };

  stage(0, 0);  // prefetch first tile before anything else

  // Q fragments for both row-groups; RoPE + scale*log2e applied in-register.
  // Lane n=l16 -> q row q0+g*64+wave*16+l16, holds d = ks*32+quad*8+j.
  bf16x8 qf[2][4];
#pragma unroll
  for (int g = 0; g < 2; g++) {
    const int t_row = q0 + g * 64 + wave * 16 + l16;
    const bf16_t* qptr = qkv + (size_t)(b * T_ + t_row) * NQKV + h * HD_;
    bf16x8 qraw[4];
#pragma unroll
    for (int ks = 0; ks < 4; ks++)
      qraw[ks] = *(const bf16x8*)(qptr + ks * 32 + quad * 8);
    const float scale = 0.12751651541057752f;  // 1/sqrt(128)*log2(e)
#pragma unroll
    for (int ks = 0; ks < 2; ks++)
#pragma unroll
      for (int j = 0; j < 8; j++) {
        int d = ks * 32 + quad * 8 + j;        // < 64
        float ang = (float)t_row * __expf(-0.14391156816f * (float)d);
        float sn, cs;
        __sincosf(ang, &sn, &cs);
        float lo = (float)qraw[ks][j], hi = (float)qraw[ks + 2][j];
        qf[g][ks][j]     = (bf16_t)((lo * cs - hi * sn) * scale);
        qf[g][ks + 2][j] = (bf16_t)((hi * cs + lo * sn) * scale);
      }
  }

  // O^T accumulators: o[g][dt][r] = O^T[d = dt*16+quad*4+r][q-row group g]
  floatx4 o[2][8];
#pragma unroll
  for (int g = 0; g < 2; g++)
#pragma unroll
    for (int i = 0; i < 8; i++) o[g][i] = floatx4{0.f, 0.f, 0.f, 0.f};
  float m_s[2] = {-1e30f, -1e30f}, l_s[2] = {0.f, 0.f};

  const int qlocal64 = wave * 16 + l16;       // q position within its 64-row group

  for (int kt = 0; kt <= ktLast; kt++) {
    const int bufi = kt & 1;
    // barrier: (a) drains vmcnt -> staging of THIS tile (issued last iter) done;
    // (b) all waves finished compute on the buffer we are about to overwrite.
    __syncthreads();
    if (kt < ktLast) stage(kt + 1, bufi ^ 1);  // prefetch next tile (other buffer)

    // S^T = K Q^T for both groups: s[g][nt][r] = S^T[key=nt*16+quad*4+r][q grp g]
    floatx4 s[2][4];
#pragma unroll
    for (int g = 0; g < 2; g++)
#pragma unroll
      for (int nt = 0; nt < 4; nt++) s[g][nt] = floatx4{0.f, 0.f, 0.f, 0.f};
    __builtin_amdgcn_s_setprio(1);
#pragma unroll
    for (int ks = 0; ks < 4; ks++) {
      int grp = ks * 4 + quad;
#pragma unroll
      for (int nt = 0; nt < 4; nt++) {
        int row = nt * 16 + l16;
        bf16x8 kf = *(const bf16x8*)(&Ks[bufi][row * 128 + ((grp ^ (row & 15)) << 3)]);
        s[0][nt] = __builtin_amdgcn_mfma_f32_16x16x32_bf16(kf, qf[0][ks], s[0][nt], 0, 0, 0);
        s[1][nt] = __builtin_amdgcn_mfma_f32_16x16x32_bf16(kf, qf[1][ks], s[1][nt], 0, 0, 0);
      }
    }
    __builtin_amdgcn_s_setprio(0);

    // causal mask per group: group g's diagonal tile is kt == 2*qt2+g; beyond
    // it (only g=0 at kt==ktLast) koff=64 > qlocal64 masks everything.
#pragma unroll
    for (int g = 0; g < 2; g++) {
      int ktd = 2 * qt2 + g;
      if (kt >= ktd) {
        int koff = (kt - ktd) * 64;
#pragma unroll
        for (int nt = 0; nt < 4; nt++)
#pragma unroll
          for (int r = 0; r < 4; r++) {
            int klocal = nt * 16 + quad * 4 + r + koff;
            if (klocal > qlocal64) s[g][nt][r] = -1e30f;
          }
      }
    }

    // online softmax per group, exp2 domain; lane's 16 values share one q-row.
#pragma unroll
    for (int g = 0; g < 2; g++) {
      float mx = fmaxf(fmaxf(s[g][0][0], s[g][0][1]), fmaxf(s[g][0][2], s[g][0][3]));
#pragma unroll
      for (int nt = 1; nt < 4; nt++)
        mx = fmaxf(mx, fmaxf(fmaxf(s[g][nt][0], s[g][nt][1]),
                             fmaxf(s[g][nt][2], s[g][nt][3])));
      mx = fmaxf(mx, __shfl_xor(mx, 16, 64));
      mx = fmaxf(mx, __shfl_xor(mx, 32, 64));
      // T13 defer-max: only rescale when the running max grew by > 8 (exp2 dom).
      if (!__all(mx <= m_s[g] + 8.0f)) {
        float mnew = fmaxf(m_s[g], mx);
        float alpha = __builtin_amdgcn_exp2f(m_s[g] - mnew);
        m_s[g] = mnew;
        l_s[g] *= alpha;
#pragma unroll
        for (int dt = 0; dt < 8; dt++) o[g][dt] *= alpha;
      }
      float sum = 0.f;
#pragma unroll
      for (int nt = 0; nt < 4; nt++)
#pragma unroll
        for (int r = 0; r < 4; r++) {
          float p = __builtin_amdgcn_exp2f(s[g][nt][r] - m_s[g]);
          s[g][nt][r] = p;
          sum += p;
        }
      sum += __shfl_xor(sum, 16, 64);
      sum += __shfl_xor(sum, 32, 64);
      l_s[g] += sum;
    }

    // O^T += V^T P^T, register-resident P (key-permuted k-dim), shared V frags.
    __builtin_amdgcn_s_setprio(1);
#pragma unroll
    for (int ks = 0; ks < 2; ks++) {
      bf16x8 pf0, pf1;
#pragma unroll
      for (int j = 0; j < 4; j++) {
        pf0[j]     = (bf16_t)s[0][ks][j];
        pf0[j + 4] = (bf16_t)s[0][ks + 2][j];
        pf1[j]     = (bf16_t)s[1][ks][j];
        pf1[j + 4] = (bf16_t)s[1][ks + 2][j];
      }
      const int G = ks * 4 + quad;   // interleaved granule: matches pf key order
#pragma unroll
      for (int dt = 0; dt < 8; dt++) {
        int row = dt * 16 + l16;
        bf16x8 vf = *(const bf16x8*)(&Vs[bufi][row * 64 + ((G ^ (row & 7)) << 3)]);
        o[0][dt] = __builtin_amdgcn_mfma_f32_16x16x32_bf16(vf, pf0, o[0][dt], 0, 0, 0);
        o[1][dt] = __builtin_amdgcn_mfma_f32_16x16x32_bf16(vf, pf1, o[1][dt], 0, 0, 0);
      }
    }
    __builtin_amdgcn_s_setprio(0);
  }

  // epilogue: lane owns q-rows q0+g*64+wave*16+l16; d = dt*16+quad*4+r.
#pragma unroll
  for (int g = 0; g < 2; g++) {
    int qg = q0 + g * 64 + wave * 16 + l16;
    float inv_l = 1.f / l_s[g];
    size_t base = ((size_t)(b * T_) + qg) * D_ + h * HD_;
#pragma unroll
    for (int dt = 0; dt < 8; dt++) {
      bf16x4 w;
#pragma unroll
      for (int r = 0; r < 4; r++) w[r] = (bf16_t)(o[g][dt][r] * inv_l);
      *(bf16x4*)(Ob + base + dt * 16 + quad * 4) = w;
    }
  }
}

// ---------------------------------------------------------------------------
extern "C" void kernel_launch(void* const* d_in, const int* in_sizes, int n_in,
                              void* d_out, int out_size, void* d_ws, size_t ws_size,
                              hipStream_t stream) {
  const float* x  = (const float*)d_in[0];
  const float* wq = (const float*)d_in[1];
  const float* wk = (const float*)d_in[2];
  const float* wv = (const float*)d_in[3];
  const float* wo = (const float*)d_in[4];
  float* out = (float*)d_out;

  // workspace layout (bf16 elems); attn output aliases x_bf (x_bf dead after GEMM1)
  bf16_t* x_bf   = (bf16_t*)d_ws;                          // 4096*2048
  bf16_t* attn_o = x_bf;                                   // alias
  bf16_t* wqkv_t = x_bf + (size_t)MROWS * D_;              // 3072*2048
  bf16_t* wo_t   = wqkv_t + (size_t)NQKV * D_;             // 2048*2048
  bf16_t* qkv    = wo_t + (size_t)D_ * D_;                 // 4096*3072
  bf16_t* Kb     = qkv + (size_t)MROWS * NQKV;             // 2*4*2048*128
  bf16_t* Vt     = Kb + (size_t)B_ * NKV_ * T_ * HD_;      // 2*4*128*2048

  // 1. fused prep: x cast + all 4 weight transposes in ONE dispatch
  prep_fused<<<dim3(64, 64, 5), dim3(32, 8), 0, stream>>>(
      wq, wk, wv, wo, x,
      wqkv_t, wqkv_t + (size_t)2048 * D_, wqkv_t + (size_t)2560 * D_, wo_t, x_bf);

  // 2. fused QKV projection: (4096,2048) x (2048,3072) -> bf16
  gemm_bt<bf16_t><<<(MROWS / 128) * (NQKV / 128), 256, 0, stream>>>(
      x_bf, wqkv_t, qkv, MROWS, NQKV, D_);

  // 3. fused K-RoPE + V transpose/interleave (Q-RoPE fused into flash)
  kv_prep<<<ROPE_BLOCKS + (T_ / 32) * (HD_ / 32) * B_ * NKV_, 256, 0, stream>>>(
      qkv, Kb, Vt);

  // 4. causal flash attention: v7, 128-row Q blocks, register-P, interleaved V
  flash_attn<<<B_ * NH_ * (T_ / 128), 256, 0, stream>>>(qkv, Kb, Vt, attn_o);

  // 5. output projection: (4096,2048) x (2048,2048) -> fp32
  gemm_bt<float><<<(MROWS / 128) * (D_ / 128), 256, 0, stream>>>(
      attn_o, wo_t, out, MROWS, D_, D_);
}

// Round 5
// 279.954 us; speedup vs baseline: 1.0157x; 1.0157x over previous
//
#include <hip/hip_runtime.h>
#include <hip/hip_bf16.h>
#include <math.h>

// Problem constants
#define B_   2
#define T_   2048
#define D_   2048
#define NH_  16
#define NKV_ 4
#define HD_  128
#define MROWS (B_*T_)          // 4096
#define NQKV  (NH_*HD_ + 2*NKV_*HD_)  // 3072

typedef __bf16 bf16_t;
typedef __bf16 bf16x8 __attribute__((ext_vector_type(8)));
typedef __bf16 bf16x4 __attribute__((ext_vector_type(4)));
typedef float  floatx4 __attribute__((ext_vector_type(4)));

template <int N> struct IC { static constexpr int v = N; };

// ---------------------------------------------------------------------------
// async global->LDS, 16B per lane. LDS dest must be wave-uniform base + lane*16.
__device__ __forceinline__ void async_copy16(const bf16_t* gsrc, bf16_t* ldst) {
  __builtin_amdgcn_global_load_lds(
      (const __attribute__((address_space(1))) unsigned int*)gsrc,
      (__attribute__((address_space(3))) unsigned int*)ldst, 16, 0, 0);
}

// ---------------------------------------------------------------------------
// Fused prep: z=0..3 -> transpose+cast weight z; z=4 -> elementwise cast of x.
// grid (64, 64, 5), block (32,8)
__global__ void prep_fused(const float* __restrict__ s0, const float* __restrict__ s1,
                           const float* __restrict__ s2, const float* __restrict__ s3,
                           const float* __restrict__ sx,
                           bf16_t* __restrict__ d0, bf16_t* __restrict__ d1,
                           bf16_t* __restrict__ d2, bf16_t* __restrict__ d3,
                           bf16_t* __restrict__ dx) {
  const int z = blockIdx.z;
  const int tx = threadIdx.x, ty = threadIdx.y;
  if (z == 4) {
    int i = ((blockIdx.y * 64 + blockIdx.x) * 256 + ty * 32 + tx) * 8;
    float4 a = *(const float4*)(sx + i);
    float4 b = *(const float4*)(sx + i + 4);
    bf16x8 v;
    v[0]=(bf16_t)a.x; v[1]=(bf16_t)a.y; v[2]=(bf16_t)a.z; v[3]=(bf16_t)a.w;
    v[4]=(bf16_t)b.x; v[5]=(bf16_t)b.y; v[6]=(bf16_t)b.z; v[7]=(bf16_t)b.w;
    *(bf16x8*)(dx + i) = v;
    return;
  }
  const int N = (z == 1 || z == 2) ? 512 : 2048;
  const int n0 = blockIdx.x * 32;
  if (n0 >= N) return;
  const float* src = (z == 0) ? s0 : (z == 1) ? s1 : (z == 2) ? s2 : s3;
  bf16_t*      dst = (z == 0) ? d0 : (z == 1) ? d1 : (z == 2) ? d2 : d3;
  const int K = 2048;
  __shared__ float tile[32][33];
  int k0 = blockIdx.y * 32;
#pragma unroll
  for (int r = 0; r < 4; r++)
    tile[ty + r*8][tx] = src[(size_t)(k0 + ty + r*8) * N + n0 + tx];
  __syncthreads();
#pragma unroll
  for (int r = 0; r < 4; r++)
    dst[(size_t)(n0 + ty + r*8) * K + k0 + tx] = (bf16_t)tile[tx][ty + r*8];
}

// ---------------------------------------------------------------------------
// C(M,N) = A(M,K) * Bt(N,K)^T   all bf16 in, OUT_T out.
// 128x128 tile, BK=64, 4 waves (2x2 of 64x64), 16x16x32 MFMA.
template <typename OUT_T>
__global__ __launch_bounds__(256, 3)
void gemm_bt(const bf16_t* __restrict__ A, const bf16_t* __restrict__ Bt,
             OUT_T* __restrict__ C, int M, int N, int K) {
  __shared__ __align__(16) bf16_t As[128 * 64];
  __shared__ __align__(16) bf16_t Bs[128 * 64];
  const int tid  = threadIdx.x;
  const int wave = tid >> 6, lane = tid & 63;
  const int quad = lane >> 4, l16 = lane & 15;
  const int nBlocksM = M >> 7;
  const int bm = blockIdx.x % nBlocksM, bn = blockIdx.x / nBlocksM;
  const int m0 = bm * 128, n0 = bn * 128;
  const int wm = (wave >> 1) * 64, wn = (wave & 1) * 64;

  floatx4 acc[4][4];
#pragma unroll
  for (int i = 0; i < 4; i++)
#pragma unroll
    for (int j = 0; j < 4; j++) acc[i][j] = floatx4{0.f, 0.f, 0.f, 0.f};

  for (int k0 = 0; k0 < K; k0 += 64) {
    __syncthreads();
#pragma unroll
    for (int i = 0; i < 4; i++) {
      int e = i * 256 + tid;
      int row = e >> 3, grp = e & 7;
      int gg = grp ^ (row & 7);
      async_copy16(A + (size_t)(m0 + row) * K + k0 + gg * 8, As + e * 8);
    }
#pragma unroll
    for (int i = 0; i < 4; i++) {
      int e = i * 256 + tid;
      int row = e >> 3, grp = e & 7;
      int gg = grp ^ (row & 7);
      async_copy16(Bt + (size_t)(n0 + row) * K + k0 + gg * 8, Bs + e * 8);
    }
    __syncthreads();
#pragma unroll
    for (int ks = 0; ks < 2; ks++) {
      bf16x8 af[4], bfr[4];
      int grp = ks * 4 + quad;
#pragma unroll
      for (int mi = 0; mi < 4; mi++) {
        int row = wm + mi * 16 + l16;
        af[mi] = *(const bf16x8*)(As + row * 64 + ((grp ^ (row & 7)) << 3));
      }
#pragma unroll
      for (int ni = 0; ni < 4; ni++) {
        int row = wn + ni * 16 + l16;
        bfr[ni] = *(const bf16x8*)(Bs + row * 64 + ((grp ^ (row & 7)) << 3));
      }
#pragma unroll
      for (int mi = 0; mi < 4; mi++)
#pragma unroll
        for (int ni = 0; ni < 4; ni++)
          acc[mi][ni] = __builtin_amdgcn_mfma_f32_16x16x32_bf16(af[mi], bfr[ni], acc[mi][ni], 0, 0, 0);
    }
  }
#pragma unroll
  for (int mi = 0; mi < 4; mi++) {
#pragma unroll
    for (int r = 0; r < 4; r++) {
      int row = m0 + wm + mi * 16 + quad * 4 + r;
      size_t base = (size_t)row * N + n0 + wn;
#pragma unroll
      for (int ni = 0; ni < 4; ni++)
        C[base + ni * 16 + l16] = (OUT_T)acc[mi][ni][r];
    }
  }
}

// ---------------------------------------------------------------------------
// Fused K-RoPE + V-transpose (one dispatch; branch is block-uniform).
// V is written INTERLEAVED in global: within each 64-key tile, key
// k = 16ks+4q+32hi+r (ks<2,q<4,hi<2,r<4) is stored at pos = ((ks*4+q)<<3)|(hi<<2)|r.
// So each 16B granule G=ks*4+q of a d-row holds keys [16ks+4q+0..3 | +32..35] —
// exactly the register-P PV fragment order; flash stages it with plain copy16.
#define ROPE_BLOCKS ((MROWS * NKV_ * 64) / 256)   // 4096
__global__ void kv_prep(const bf16_t* __restrict__ qkv, bf16_t* __restrict__ Kb,
                        bf16_t* __restrict__ Vt) {
  if (blockIdx.x < ROPE_BLOCKS) {
    int g = blockIdx.x * 256 + threadIdx.x;
    int j = g & 63;
    int rest = g >> 6;
    int kvh = rest & 3;
    int row = rest >> 2;                // b*T + t
    int t = row & (T_ - 1);
    int b = row >> 11;                  // T_ = 2048
    const bf16_t* src = qkv + (size_t)row * NQKV + NH_ * HD_ + kvh * HD_;
    float ang = (float)t * __expf(-0.14391156816f * (float)j);
    float sn, cs;
    __sincosf(ang, &sn, &cs);
    float x0 = (float)src[j];
    float x1 = (float)src[j + 64];
    bf16_t* dst = Kb + ((size_t)(b * NKV_ + kvh) * T_ + t) * HD_;
    dst[j]      = (bf16_t)(x0 * cs - x1 * sn);
    dst[j + 64] = (bf16_t)(x1 * cs + x0 * sn);
    return;
  }
  __shared__ float tile[32][33];
  int bb = blockIdx.x - ROPE_BLOCKS;          // [0, 2048)
  int bx = bb & 63, by = (bb >> 6) & 3, bz = bb >> 8;
  int t0 = bx * 32, d0 = by * 32;
  int b = bz / NKV_, kvh = bz % NKV_;
  int tx = threadIdx.x & 31, ty = threadIdx.x >> 5;
#pragma unroll
  for (int r = 0; r < 4; r++) {
    int t = t0 + ty + r * 8;
    tile[ty + r*8][tx] =
        (float)qkv[(size_t)(b * T_ + t) * NQKV + (NH_ + NKV_) * HD_ + kvh * HD_ + d0 + tx];
  }
  __syncthreads();
#pragma unroll
  for (int r = 0; r < 4; r++) {
    int d = d0 + ty + r * 8;
    int t = t0 + tx;
    int k = t & 63;
    int pos = ((((k >> 4) & 1) * 4 + ((k >> 2) & 3)) << 3) + ((k >> 5) << 2) + (k & 3);
    Vt[((size_t)(b * NKV_ + kvh) * HD_ + d) * T_ + (t & ~63) + pos] =
        (bf16_t)tile[tx][ty + r*8];
  }
}

// ---------------------------------------------------------------------------
// Flash attention v8: CAUSAL FOLD — equal-work blocks + shared K/V LDS reads.
//
// Measured model (r4): v6/v7 are LDS-read-throughput bound: per wave-tile
// 32x ds_read_b128 (~384cy) vs 155-310cy MFMA. Sharing each K/V fragment
// across 2 q-groups halves LDS-cy/FLOP (v7), but v7's (2a,2a+1) pairing made
// block work triangular in qt -> intra-CU serial tails (occupancy 12.7%).
//
// v8 pairs q-tiles (j, 31-j) in ONE block ("fold"): group B (qt=31-j) runs
// kt=0..31-j; group A (qt=j) co-computes on kt<=j sharing the same K/V reads.
// Per-wave MFMA per block = (j+1)*64 + (31-2j)*32 = 1056 for ALL j: every
// block equal-work -> makespan independent of dispatch placement (no pairing
// assumptions). Tile body is constexpr-dispatched on NG (2 groups vs 1).
//
// + register-P PV (key-permuted k-dim), interleaved-V global layout,
//   T13 defer-max, T5 setprio, in-register Q-RoPE (all verified earlier).
__global__ __launch_bounds__(256, 2)
void flash_attn(const bf16_t* __restrict__ qkv, const bf16_t* __restrict__ Kb,
                const bf16_t* __restrict__ Vt, bf16_t* __restrict__ Ob) {
  __shared__ __align__(16) bf16_t Ks[2][64 * 128];   // (key, d), swizzle grp^(row&15)
  __shared__ __align__(16) bf16_t Vs[2][128 * 64];   // (d, key-interleaved), swz grp^(row&7)

  const int tid = threadIdx.x;
  const int wave = tid >> 6, lane = tid & 63;
  const int quad = lane >> 4, l16 = lane & 15;
  const int bid = blockIdx.x;
  const int bh = bid & 31;                    // (b,h)
  const int jA = bid >> 5;                    // 0..15  (group A q-tile)
  const int qtB = 31 - jA;                    // 16..31 (group B q-tile)
  const int h = bh & 15;
  const int b = bh >> 4;
  const int kv = h >> 2;                      // GQA: n_rep = 4
  const int ktB = qtB;                        // last kv-tile (B's diagonal)

  const bf16_t* kbase = Kb + ((size_t)(b * NKV_ + kv) * T_) * HD_;
  const bf16_t* vbase = Vt + ((size_t)(b * NKV_ + kv) * HD_) * T_;

  auto stage = [&](int kt, int bufi) {
#pragma unroll
    for (int i = 0; i < 4; i++) {
      int e = i * 256 + tid;
      int row = e >> 4, grp = e & 15;
      int gg = grp ^ (row & 15);
      async_copy16(kbase + (size_t)(kt * 64 + row) * HD_ + gg * 8, &Ks[bufi][e * 8]);
    }
#pragma unroll
    for (int i = 0; i < 4; i++) {
      int e = i * 256 + tid;
      int row = e >> 3, grp = e & 7;
      int gg = grp ^ (row & 7);
      async_copy16(vbase + (size_t)row * T_ + kt * 64 + gg * 8, &Vs[bufi][e * 8]);
    }
  };

  stage(0, 0);  // prefetch first tile before anything else

  // q-tile per group: g=0 -> B (always active), g=1 -> A (active for kt<=jA)
  const int qt_g[2] = { qtB, jA };

  // Q fragments; RoPE + scale*log2e applied in-register.
  // Lane n=l16 -> q row qt_g[g]*64+wave*16+l16, holds d = ks*32+quad*8+j.
  bf16x8 qf[2][4];
#pragma unroll
  for (int g = 0; g < 2; g++) {
    const int t_row = qt_g[g] * 64 + wave * 16 + l16;
    const bf16_t* qptr = qkv + (size_t)(b * T_ + t_row) * NQKV + h * HD_;
    bf16x8 qraw[4];
#pragma unroll
    for (int ks = 0; ks < 4; ks++)
      qraw[ks] = *(const bf16x8*)(qptr + ks * 32 + quad * 8);
    const float scale = 0.12751651541057752f;  // 1/sqrt(128)*log2(e)
#pragma unroll
    for (int ks = 0; ks < 2; ks++)
#pragma unroll
      for (int j = 0; j < 8; j++) {
        int d = ks * 32 + quad * 8 + j;        // < 64
        float ang = (float)t_row * __expf(-0.14391156816f * (float)d);
        float sn, cs;
        __sincosf(ang, &sn, &cs);
        float lo = (float)qraw[ks][j], hi = (float)qraw[ks + 2][j];
        qf[g][ks][j]     = (bf16_t)((lo * cs - hi * sn) * scale);
        qf[g][ks + 2][j] = (bf16_t)((hi * cs + lo * sn) * scale);
      }
  }

  // O^T accumulators: o[g][dt][r] = O^T[d = dt*16+quad*4+r][q-row group g]
  floatx4 o[2][8];
#pragma unroll
  for (int g = 0; g < 2; g++)
#pragma unroll
    for (int i = 0; i < 8; i++) o[g][i] = floatx4{0.f, 0.f, 0.f, 0.f};
  float m_s[2] = {-1e30f, -1e30f}, l_s[2] = {0.f, 0.f};

  const int qlocal64 = wave * 16 + l16;       // q position within its 64-row group

  for (int kt = 0; kt <= ktB; kt++) {
    const int bufi = kt & 1;
    // barrier: (a) drains vmcnt -> staging of THIS tile (issued last iter) done;
    // (b) all waves finished compute on the buffer we are about to overwrite.
    __syncthreads();
    if (kt < ktB) stage(kt + 1, bufi ^ 1);  // prefetch next tile (other buffer)

    auto body = [&](auto ngc) {
      constexpr int NG = decltype(ngc)::v;
      // S^T = K Q^T: s[g][nt][r] = S^T[key=nt*16+quad*4+r][q grp g]
      floatx4 s[NG][4];
#pragma unroll
      for (int g = 0; g < NG; g++)
#pragma unroll
        for (int nt = 0; nt < 4; nt++) s[g][nt] = floatx4{0.f, 0.f, 0.f, 0.f};
      __builtin_amdgcn_s_setprio(1);
#pragma unroll
      for (int ks = 0; ks < 4; ks++) {
        int grp = ks * 4 + quad;
#pragma unroll
        for (int nt = 0; nt < 4; nt++) {
          int row = nt * 16 + l16;
          bf16x8 kf = *(const bf16x8*)(&Ks[bufi][row * 128 + ((grp ^ (row & 15)) << 3)]);
#pragma unroll
          for (int g = 0; g < NG; g++)
            s[g][nt] = __builtin_amdgcn_mfma_f32_16x16x32_bf16(kf, qf[g][ks], s[g][nt], 0, 0, 0);
        }
      }
      __builtin_amdgcn_s_setprio(0);

      // causal mask: group g's diagonal tile is kt == qt_g[g]; no other tile
      // in its active range needs masking.
#pragma unroll
      for (int g = 0; g < NG; g++) {
        if (kt == qt_g[g]) {
#pragma unroll
          for (int nt = 0; nt < 4; nt++)
#pragma unroll
            for (int r = 0; r < 4; r++) {
              int klocal = nt * 16 + quad * 4 + r;
              if (klocal > qlocal64) s[g][nt][r] = -1e30f;
            }
        }
      }

      // online softmax per group, exp2 domain; lane's 16 vals share one q-row.
#pragma unroll
      for (int g = 0; g < NG; g++) {
        float mx = fmaxf(fmaxf(s[g][0][0], s[g][0][1]), fmaxf(s[g][0][2], s[g][0][3]));
#pragma unroll
        for (int nt = 1; nt < 4; nt++)
          mx = fmaxf(mx, fmaxf(fmaxf(s[g][nt][0], s[g][nt][1]),
                               fmaxf(s[g][nt][2], s[g][nt][3])));
        mx = fmaxf(mx, __shfl_xor(mx, 16, 64));
        mx = fmaxf(mx, __shfl_xor(mx, 32, 64));
        // T13 defer-max: only rescale when the running max grew by > 8.
        if (!__all(mx <= m_s[g] + 8.0f)) {
          float mnew = fmaxf(m_s[g], mx);
          float alpha = __builtin_amdgcn_exp2f(m_s[g] - mnew);
          m_s[g] = mnew;
          l_s[g] *= alpha;
#pragma unroll
          for (int dt = 0; dt < 8; dt++) o[g][dt] *= alpha;
        }
        float sum = 0.f;
#pragma unroll
        for (int nt = 0; nt < 4; nt++)
#pragma unroll
          for (int r = 0; r < 4; r++) {
            float p = __builtin_amdgcn_exp2f(s[g][nt][r] - m_s[g]);
            s[g][nt][r] = p;
            sum += p;
          }
        sum += __shfl_xor(sum, 16, 64);
        sum += __shfl_xor(sum, 32, 64);
        l_s[g] += sum;
      }

      // O^T += V^T P^T, register-resident P (key-permuted), shared V frags.
      __builtin_amdgcn_s_setprio(1);
#pragma unroll
      for (int ks = 0; ks < 2; ks++) {
        bf16x8 pf[NG];
#pragma unroll
        for (int g = 0; g < NG; g++)
#pragma unroll
          for (int j = 0; j < 4; j++) {
            pf[g][j]     = (bf16_t)s[g][ks][j];
            pf[g][j + 4] = (bf16_t)s[g][ks + 2][j];
          }
        const int G = ks * 4 + quad;   // interleaved granule: matches pf key order
#pragma unroll
        for (int dt = 0; dt < 8; dt++) {
          int row = dt * 16 + l16;
          bf16x8 vf = *(const bf16x8*)(&Vs[bufi][row * 64 + ((G ^ (row & 7)) << 3)]);
#pragma unroll
          for (int g = 0; g < NG; g++)
            o[g][dt] = __builtin_amdgcn_mfma_f32_16x16x32_bf16(vf, pf[g], o[g][dt], 0, 0, 0);
        }
      }
      __builtin_amdgcn_s_setprio(0);
    };

    if (kt <= jA) body(IC<2>{});   // both groups active (shared reads)
    else          body(IC<1>{});   // group B only

  }

  // epilogue: lane owns q-rows qt_g[g]*64+wave*16+l16; d = dt*16+quad*4+r.
#pragma unroll
  for (int g = 0; g < 2; g++) {
    int qg = qt_g[g] * 64 + wave * 16 + l16;
    float inv_l = 1.f / l_s[g];
    size_t base = ((size_t)(b * T_) + qg) * D_ + h * HD_;
#pragma unroll
    for (int dt = 0; dt < 8; dt++) {
      bf16x4 w;
#pragma unroll
      for (int r = 0; r < 4; r++) w[r] = (bf16_t)(o[g][dt][r] * inv_l);
      *(bf16x4*)(Ob + base + dt * 16 + quad * 4) = w;
    }
  }
}

// ---------------------------------------------------------------------------
extern "C" void kernel_launch(void* const* d_in, const int* in_sizes, int n_in,
                              void* d_out, int out_size, void* d_ws, size_t ws_size,
                              hipStream_t stream) {
  const float* x  = (const float*)d_in[0];
  const float* wq = (const float*)d_in[1];
  const float* wk = (const float*)d_in[2];
  const float* wv = (const float*)d_in[3];
  const float* wo = (const float*)d_in[4];
  float* out = (float*)d_out;

  // workspace layout (bf16 elems); attn output aliases x_bf (x_bf dead after GEMM1)
  bf16_t* x_bf   = (bf16_t*)d_ws;                          // 4096*2048
  bf16_t* attn_o = x_bf;                                   // alias
  bf16_t* wqkv_t = x_bf + (size_t)MROWS * D_;              // 3072*2048
  bf16_t* wo_t   = wqkv_t + (size_t)NQKV * D_;             // 2048*2048
  bf16_t* qkv    = wo_t + (size_t)D_ * D_;                 // 4096*3072
  bf16_t* Kb     = qkv + (size_t)MROWS * NQKV;             // 2*4*2048*128
  bf16_t* Vt     = Kb + (size_t)B_ * NKV_ * T_ * HD_;      // 2*4*128*2048

  // 1. fused prep: x cast + all 4 weight transposes in ONE dispatch
  prep_fused<<<dim3(64, 64, 5), dim3(32, 8), 0, stream>>>(
      wq, wk, wv, wo, x,
      wqkv_t, wqkv_t + (size_t)2048 * D_, wqkv_t + (size_t)2560 * D_, wo_t, x_bf);

  // 2. fused QKV projection: (4096,2048) x (2048,3072) -> bf16
  gemm_bt<bf16_t><<<(MROWS / 128) * (NQKV / 128), 256, 0, stream>>>(
      x_bf, wqkv_t, qkv, MROWS, NQKV, D_);

  // 3. fused K-RoPE + V transpose/interleave (Q-RoPE fused into flash)
  kv_prep<<<ROPE_BLOCKS + (T_ / 32) * (HD_ / 32) * B_ * NKV_, 256, 0, stream>>>(
      qkv, Kb, Vt);

  // 4. causal flash attention: v8, fold-paired equal-work blocks
  flash_attn<<<B_ * NH_ * (T_ / 128), 256, 0, stream>>>(qkv, Kb, Vt, attn_o);

  // 5. output projection: (4096,2048) x (2048,2048) -> fp32
  gemm_bt<float><<<(MROWS / 128) * (D_ / 128), 256, 0, stream>>>(
      attn_o, wo_t, out, MROWS, D_, D_);
}

// Round 7
// 270.162 us; speedup vs baseline: 1.0525x; 1.0362x over previous
//
#include <hip/hip_runtime.h>
#include <hip/hip_bf16.h>
#include <math.h>

// Problem constants
#define B_   2
#define T_   2048
#define D_   2048
#define NH_  16
#define NKV_ 4
#define HD_  128
#define MROWS (B_*T_)          // 4096
#define NQKV  (NH_*HD_ + 2*NKV_*HD_)  // 3072

typedef __bf16 bf16_t;
typedef __bf16 bf16x8 __attribute__((ext_vector_type(8)));
typedef __bf16 bf16x4 __attribute__((ext_vector_type(4)));
typedef float  floatx4 __attribute__((ext_vector_type(4)));

// ---------------------------------------------------------------------------
// async global->LDS, 16B per lane. LDS dest must be wave-uniform base + lane*16.
__device__ __forceinline__ void async_copy16(const bf16_t* gsrc, bf16_t* ldst) {
  __builtin_amdgcn_global_load_lds(
      (const __attribute__((address_space(1))) unsigned int*)gsrc,
      (__attribute__((address_space(3))) unsigned int*)ldst, 16, 0, 0);
}

// ---------------------------------------------------------------------------
// Fused prep: z=0..3 -> transpose+cast weight z; z=4 -> elementwise cast of x.
// grid (64, 64, 5), block (32,8)
__global__ void prep_fused(const float* __restrict__ s0, const float* __restrict__ s1,
                           const float* __restrict__ s2, const float* __restrict__ s3,
                           const float* __restrict__ sx,
                           bf16_t* __restrict__ d0, bf16_t* __restrict__ d1,
                           bf16_t* __restrict__ d2, bf16_t* __restrict__ d3,
                           bf16_t* __restrict__ dx) {
  const int z = blockIdx.z;
  const int tx = threadIdx.x, ty = threadIdx.y;
  if (z == 4) {
    int i = ((blockIdx.y * 64 + blockIdx.x) * 256 + ty * 32 + tx) * 8;
    float4 a = *(const float4*)(sx + i);
    float4 b = *(const float4*)(sx + i + 4);
    bf16x8 v;
    v[0]=(bf16_t)a.x; v[1]=(bf16_t)a.y; v[2]=(bf16_t)a.z; v[3]=(bf16_t)a.w;
    v[4]=(bf16_t)b.x; v[5]=(bf16_t)b.y; v[6]=(bf16_t)b.z; v[7]=(bf16_t)b.w;
    *(bf16x8*)(dx + i) = v;
    return;
  }
  const int N = (z == 1 || z == 2) ? 512 : 2048;
  const int n0 = blockIdx.x * 32;
  if (n0 >= N) return;
  const float* src = (z == 0) ? s0 : (z == 1) ? s1 : (z == 2) ? s2 : s3;
  bf16_t*      dst = (z == 0) ? d0 : (z == 1) ? d1 : (z == 2) ? d2 : d3;
  const int K = 2048;
  __shared__ float tile[32][33];
  int k0 = blockIdx.y * 32;
#pragma unroll
  for (int r = 0; r < 4; r++)
    tile[ty + r*8][tx] = src[(size_t)(k0 + ty + r*8) * N + n0 + tx];
  __syncthreads();
#pragma unroll
  for (int r = 0; r < 4; r++)
    dst[(size_t)(n0 + ty + r*8) * K + k0 + tx] = (bf16_t)tile[tx][ty + r*8];
}

// ---------------------------------------------------------------------------
// C(M,N) = A(M,K) * Bt(N,K)^T   all bf16 in, OUT_T out.
// 128x128 tile, BK=64, 4 waves (2x2 of 64x64), 16x16x32 MFMA.
template <typename OUT_T>
__global__ __launch_bounds__(256, 3)
void gemm_bt(const bf16_t* __restrict__ A, const bf16_t* __restrict__ Bt,
             OUT_T* __restrict__ C, int M, int N, int K) {
  __shared__ __align__(16) bf16_t As[128 * 64];
  __shared__ __align__(16) bf16_t Bs[128 * 64];
  const int tid  = threadIdx.x;
  const int wave = tid >> 6, lane = tid & 63;
  const int quad = lane >> 4, l16 = lane & 15;
  const int nBlocksM = M >> 7;
  const int bm = blockIdx.x % nBlocksM, bn = blockIdx.x / nBlocksM;
  const int m0 = bm * 128, n0 = bn * 128;
  const int wm = (wave >> 1) * 64, wn = (wave & 1) * 64;

  floatx4 acc[4][4];
#pragma unroll
  for (int i = 0; i < 4; i++)
#pragma unroll
    for (int j = 0; j < 4; j++) acc[i][j] = floatx4{0.f, 0.f, 0.f, 0.f};

  for (int k0 = 0; k0 < K; k0 += 64) {
    __syncthreads();
#pragma unroll
    for (int i = 0; i < 4; i++) {
      int e = i * 256 + tid;
      int row = e >> 3, grp = e & 7;
      int gg = grp ^ (row & 7);
      async_copy16(A + (size_t)(m0 + row) * K + k0 + gg * 8, As + e * 8);
    }
#pragma unroll
    for (int i = 0; i < 4; i++) {
      int e = i * 256 + tid;
      int row = e >> 3, grp = e & 7;
      int gg = grp ^ (row & 7);
      async_copy16(Bt + (size_t)(n0 + row) * K + k0 + gg * 8, Bs + e * 8);
    }
    __syncthreads();
#pragma unroll
    for (int ks = 0; ks < 2; ks++) {
      bf16x8 af[4], bfr[4];
      int grp = ks * 4 + quad;
#pragma unroll
      for (int mi = 0; mi < 4; mi++) {
        int row = wm + mi * 16 + l16;
        af[mi] = *(const bf16x8*)(As + row * 64 + ((grp ^ (row & 7)) << 3));
      }
#pragma unroll
      for (int ni = 0; ni < 4; ni++) {
        int row = wn + ni * 16 + l16;
        bfr[ni] = *(const bf16x8*)(Bs + row * 64 + ((grp ^ (row & 7)) << 3));
      }
#pragma unroll
      for (int mi = 0; mi < 4; mi++)
#pragma unroll
        for (int ni = 0; ni < 4; ni++)
          acc[mi][ni] = __builtin_amdgcn_mfma_f32_16x16x32_bf16(af[mi], bfr[ni], acc[mi][ni], 0, 0, 0);
    }
  }
#pragma unroll
  for (int mi = 0; mi < 4; mi++) {
#pragma unroll
    for (int r = 0; r < 4; r++) {
      int row = m0 + wm + mi * 16 + quad * 4 + r;
      size_t base = (size_t)row * N + n0 + wn;
#pragma unroll
      for (int ni = 0; ni < 4; ni++)
        C[base + ni * 16 + l16] = (OUT_T)acc[mi][ni][r];
    }
  }
}

// ---------------------------------------------------------------------------
// Fused K-RoPE + V-transpose (one dispatch; branch is block-uniform).
// V is written INTERLEAVED in global: within each 64-key tile, key
// k = 16ks+4q+32hi+r (ks<2,q<4,hi<2,r<4) is stored at pos = ((ks*4+q)<<3)|(hi<<2)|r.
// So each 16B granule G=ks*4+q of a d-row holds keys [16ks+4q+0..3 | +32..35] —
// exactly the register-P PV fragment order; flash stages it with plain copy16.
#define ROPE_BLOCKS ((MROWS * NKV_ * 64) / 256)   // 4096
__global__ void kv_prep(const bf16_t* __restrict__ qkv, bf16_t* __restrict__ Kb,
                        bf16_t* __restrict__ Vt) {
  if (blockIdx.x < ROPE_BLOCKS) {
    int g = blockIdx.x * 256 + threadIdx.x;
    int j = g & 63;
    int rest = g >> 6;
    int kvh = rest & 3;
    int row = rest >> 2;                // b*T + t
    int t = row & (T_ - 1);
    int b = row >> 11;                  // T_ = 2048
    const bf16_t* src = qkv + (size_t)row * NQKV + NH_ * HD_ + kvh * HD_;
    float ang = (float)t * __expf(-0.14391156816f * (float)j);
    float sn, cs;
    __sincosf(ang, &sn, &cs);
    float x0 = (float)src[j];
    float x1 = (float)src[j + 64];
    bf16_t* dst = Kb + ((size_t)(b * NKV_ + kvh) * T_ + t) * HD_;
    dst[j]      = (bf16_t)(x0 * cs - x1 * sn);
    dst[j + 64] = (bf16_t)(x1 * cs + x0 * sn);
    return;
  }
  __shared__ float tile[32][33];
  int bb = blockIdx.x - ROPE_BLOCKS;          // [0, 2048)
  int bx = bb & 63, by = (bb >> 6) & 3, bz = bb >> 8;
  int t0 = bx * 32, d0 = by * 32;
  int b = bz / NKV_, kvh = bz % NKV_;
  int tx = threadIdx.x & 31, ty = threadIdx.x >> 5;
#pragma unroll
  for (int r = 0; r < 4; r++) {
    int t = t0 + ty + r * 8;
    tile[ty + r*8][tx] =
        (float)qkv[(size_t)(b * T_ + t) * NQKV + (NH_ + NKV_) * HD_ + kvh * HD_ + d0 + tx];
  }
  __syncthreads();
#pragma unroll
  for (int r = 0; r < 4; r++) {
    int d = d0 + ty + r * 8;
    int t = t0 + tx;
    int k = t & 63;
    int pos = ((((k >> 4) & 1) * 4 + ((k >> 2) & 3)) << 3) + ((k >> 5) << 2) + (k & 3);
    Vt[((size_t)(b * NKV_ + kvh) * HD_ + d) * T_ + (t & ~63) + pos] =
        (bf16_t)tile[tx][ty + r*8];
  }
}

// ---------------------------------------------------------------------------
// Flash attention v9: 8-WAVE BLOCKS — 2x TLP on the proven v6 wave body.
//
// Evidence (r3->r4 A/B): removing 8.65M bank-conflict cycles (~14us/CU LDS
// busy) changed time by ZERO -> no pipe saturated; the kernel is dependency-
// LATENCY bound at 2 waves/SIMD. Fix occupancy, not decomposition.
//
// Block = 512 threads (8 waves), 2 q-tiles: waves 0-3 -> q-tile 2qm,
// waves 4-7 -> 2qm+1. Each wave runs the UNCHANGED v6 NG=1 body (16 q-rows,
// VGPR ~88 -> fits 4 waves/SIMD; __launch_bounds__(512,4)). LDS still 64KB
// -> 2 blocks/CU = 16 waves/CU = 4/SIMD (2x v6-v8). K/V staged once, shared
// by 8 waves. Waves 0-3 skip compute (wave-uniform branch) on the single
// tile past their diagonal. Complementary map qm = p<8 ? 15-p : p-8 makes
// likely co-residents (bid, bid+256) sum to 34 tiles; adverse placement
// degrades gracefully (tails run at 2 waves/SIMD, vs v7's 1).
//
// + register-P PV (key-permuted), interleaved-V global layout (conflicts=0),
//   T13 defer-max, T5 setprio, in-register Q-RoPE (all verified earlier).
__global__ __launch_bounds__(512, 4)
void flash_attn(const bf16_t* __restrict__ qkv, const bf16_t* __restrict__ Kb,
                const bf16_t* __restrict__ Vt, bf16_t* __restrict__ Ob) {
  __shared__ __align__(16) bf16_t Ks[2][64 * 128];   // (key, d), swizzle grp^(row&15)
  __shared__ __align__(16) bf16_t Vs[2][128 * 64];   // (d, key-interleaved), swz grp^(row&7)

  const int tid = threadIdx.x;                // 0..511
  const int wave = tid >> 6, lane = tid & 63;
  const int quad = lane >> 4, l16 = lane & 15;
  const int bid = blockIdx.x;
  const int bh = bid & 31;                    // (b,h)
  const int p  = bid >> 5;                    // 0..15
  const int qm = (p < 8) ? (15 - p) : (p - 8);  // complementary pair map
  const int h = bh & 15;
  const int b = bh >> 4;
  const int kv = h >> 2;                      // GQA: n_rep = 4
  const int wq = wave >> 2;                   // 0/1: which q-tile this wave owns
  const int w4 = wave & 3;                    // 16-row slice within the q-tile
  const int qtw = 2 * qm + wq;                // this wave's q-tile (64 rows)
  const int ktLast = 2 * qm + 1;              // block's last kv-tile

  const bf16_t* kbase = Kb + ((size_t)(b * NKV_ + kv) * T_) * HD_;
  const bf16_t* vbase = Vt + ((size_t)(b * NKV_ + kv) * HD_) * T_;

  // staging split over 512 threads: 2 rounds K (16KB) + 2 rounds V (16KB)
  auto stage = [&](int kt, int bufi) {
#pragma unroll
    for (int i = 0; i < 2; i++) {
      int e = i * 512 + tid;                  // 0..1023
      int row = e >> 4, grp = e & 15;
      int gg = grp ^ (row & 15);
      async_copy16(kbase + (size_t)(kt * 64 + row) * HD_ + gg * 8, &Ks[bufi][e * 8]);
    }
#pragma unroll
    for (int i = 0; i < 2; i++) {
      int e = i * 512 + tid;
      int row = e >> 3, grp = e & 7;
      int gg = grp ^ (row & 7);
      async_copy16(vbase + (size_t)row * T_ + kt * 64 + gg * 8, &Vs[bufi][e * 8]);
    }
  };

  stage(0, 0);  // prefetch first tile before anything else

  // Q fragments (B-operand): lane n=l16 -> q row t_row, holds d = ks*32+quad*8+j.
  bf16x8 qf[4];
  {
    const int t_row = qtw * 64 + w4 * 16 + l16;
    const bf16_t* qptr = qkv + (size_t)(b * T_ + t_row) * NQKV + h * HD_;
    bf16x8 qraw[4];
#pragma unroll
    for (int ks = 0; ks < 4; ks++)
      qraw[ks] = *(const bf16x8*)(qptr + ks * 32 + quad * 8);
    const float scale = 0.12751651541057752f;  // 1/sqrt(128)*log2(e)
#pragma unroll
    for (int ks = 0; ks < 2; ks++)
#pragma unroll
      for (int j = 0; j < 8; j++) {
        int d = ks * 32 + quad * 8 + j;        // < 64
        float ang = (float)t_row * __expf(-0.14391156816f * (float)d);
        float sn, cs;
        __sincosf(ang, &sn, &cs);
        float lo = (float)qraw[ks][j], hi = (float)qraw[ks + 2][j];
        qf[ks][j]     = (bf16_t)((lo * cs - hi * sn) * scale);
        qf[ks + 2][j] = (bf16_t)((hi * cs + lo * sn) * scale);
      }
  }

  // O^T accumulators: o[dt][r] = O^T[d = dt*16+quad*4+r][q = l16]
  floatx4 o[8];
#pragma unroll
  for (int i = 0; i < 8; i++) o[i] = floatx4{0.f, 0.f, 0.f, 0.f};
  float m_s = -1e30f, l_s = 0.f;  // per-lane: this lane's q-row state

  const int qlocal = w4 * 16 + l16;  // q position within this wave's 64-row tile

  for (int kt = 0; kt <= ktLast; kt++) {
    const int bufi = kt & 1;
    // barrier: (a) each wave's implicit vmcnt drain + barrier -> staging of
    // THIS tile (issued last iter by all waves) complete; (b) all waves done
    // computing on the buffer we are about to overwrite.
    __syncthreads();
    if (kt < ktLast) stage(kt + 1, bufi ^ 1);  // prefetch next tile (other buffer)

    if (kt <= qtw) {   // wave-uniform: waves 0-3 skip the tile past their diagonal
      // S^T = K Q^T : s[nt][r] = S^T[key = nt*16+quad*4+r][q = l16]
      floatx4 s[4];
#pragma unroll
      for (int nt = 0; nt < 4; nt++) s[nt] = floatx4{0.f, 0.f, 0.f, 0.f};
      __builtin_amdgcn_s_setprio(1);
#pragma unroll
      for (int ks = 0; ks < 4; ks++) {
        int grp = ks * 4 + quad;
#pragma unroll
        for (int nt = 0; nt < 4; nt++) {
          int row = nt * 16 + l16;
          bf16x8 kf = *(const bf16x8*)(&Ks[bufi][row * 128 + ((grp ^ (row & 15)) << 3)]);
          s[nt] = __builtin_amdgcn_mfma_f32_16x16x32_bf16(kf, qf[ks], s[nt], 0, 0, 0);
        }
      }
      __builtin_amdgcn_s_setprio(0);

      // causal mask (only this wave's diagonal tile): key_local > q_local
      if (kt == qtw) {
#pragma unroll
        for (int nt = 0; nt < 4; nt++)
#pragma unroll
          for (int r = 0; r < 4; r++) {
            int klocal = nt * 16 + quad * 4 + r;
            if (klocal > qlocal) s[nt][r] = -1e30f;
          }
      }

      // online softmax, exp2 domain; lane's 16 values share one q-row.
      float mx = fmaxf(fmaxf(s[0][0], s[0][1]), fmaxf(s[0][2], s[0][3]));
#pragma unroll
      for (int nt = 1; nt < 4; nt++)
        mx = fmaxf(mx, fmaxf(fmaxf(s[nt][0], s[nt][1]), fmaxf(s[nt][2], s[nt][3])));
      mx = fmaxf(mx, __shfl_xor(mx, 16, 64));
      mx = fmaxf(mx, __shfl_xor(mx, 32, 64));
      // T13 defer-max: only rescale when the running max grew by > 8 (exp2 dom).
      if (!__all(mx <= m_s + 8.0f)) {
        float mnew = fmaxf(m_s, mx);
        float alpha = __builtin_amdgcn_exp2f(m_s - mnew);
        m_s = mnew;
        l_s *= alpha;
#pragma unroll
        for (int dt = 0; dt < 8; dt++) o[dt] *= alpha;
      }
      float sum = 0.f;
#pragma unroll
      for (int nt = 0; nt < 4; nt++)
#pragma unroll
        for (int r = 0; r < 4; r++) {
          float pv = __builtin_amdgcn_exp2f(s[nt][r] - m_s);
          s[nt][r] = pv;
          sum += pv;
        }
      sum += __shfl_xor(sum, 16, 64);
      sum += __shfl_xor(sum, 32, 64);
      l_s += sum;

      // O^T += V^T P^T, register-resident P, single b128 V read per MFMA.
      __builtin_amdgcn_s_setprio(1);
#pragma unroll
      for (int ks = 0; ks < 2; ks++) {
        bf16x8 pf;
#pragma unroll
        for (int j = 0; j < 4; j++) {
          pf[j]     = (bf16_t)s[ks][j];
          pf[j + 4] = (bf16_t)s[ks + 2][j];
        }
        const int G = ks * 4 + quad;   // interleaved granule: matches pf key order
#pragma unroll
        for (int dt = 0; dt < 8; dt++) {
          int row = dt * 16 + l16;
          bf16x8 vf = *(const bf16x8*)(&Vs[bufi][row * 64 + ((G ^ (row & 7)) << 3)]);
          o[dt] = __builtin_amdgcn_mfma_f32_16x16x32_bf16(vf, pf, o[dt], 0, 0, 0);
        }
      }
      __builtin_amdgcn_s_setprio(0);
    }
  }

  // epilogue: lane owns q-row qg = qtw*64 + w4*16 + l16; d = dt*16+quad*4+r.
  {
    int qg = qtw * 64 + w4 * 16 + l16;
    float inv_l = 1.f / l_s;
    size_t base = ((size_t)(b * T_) + qg) * D_ + h * HD_;
#pragma unroll
    for (int dt = 0; dt < 8; dt++) {
      bf16x4 w;
#pragma unroll
      for (int r = 0; r < 4; r++) w[r] = (bf16_t)(o[dt][r] * inv_l);
      *(bf16x4*)(Ob + base + dt * 16 + quad * 4) = w;
    }
  }
}

// ---------------------------------------------------------------------------
extern "C" void kernel_launch(void* const* d_in, const int* in_sizes, int n_in,
                              void* d_out, int out_size, void* d_ws, size_t ws_size,
                              hipStream_t stream) {
  const float* x  = (const float*)d_in[0];
  const float* wq = (const float*)d_in[1];
  const float* wk = (const float*)d_in[2];
  const float* wv = (const float*)d_in[3];
  const float* wo = (const float*)d_in[4];
  float* out = (float*)d_out;

  // workspace layout (bf16 elems); attn output aliases x_bf (x_bf dead after GEMM1)
  bf16_t* x_bf   = (bf16_t*)d_ws;                          // 4096*2048
  bf16_t* attn_o = x_bf;                                   // alias
  bf16_t* wqkv_t = x_bf + (size_t)MROWS * D_;              // 3072*2048
  bf16_t* wo_t   = wqkv_t + (size_t)NQKV * D_;             // 2048*2048
  bf16_t* qkv    = wo_t + (size_t)D_ * D_;                 // 4096*3072
  bf16_t* Kb     = qkv + (size_t)MROWS * NQKV;             // 2*4*2048*128
  bf16_t* Vt     = Kb + (size_t)B_ * NKV_ * T_ * HD_;      // 2*4*128*2048

  // 1. fused prep: x cast + all 4 weight transposes in ONE dispatch
  prep_fused<<<dim3(64, 64, 5), dim3(32, 8), 0, stream>>>(
      wq, wk, wv, wo, x,
      wqkv_t, wqkv_t + (size_t)2048 * D_, wqkv_t + (size_t)2560 * D_, wo_t, x_bf);

  // 2. fused QKV projection: (4096,2048) x (2048,3072) -> bf16
  gemm_bt<bf16_t><<<(MROWS / 128) * (NQKV / 128), 256, 0, stream>>>(
      x_bf, wqkv_t, qkv, MROWS, NQKV, D_);

  // 3. fused K-RoPE + V transpose/interleave (Q-RoPE fused into flash)
  kv_prep<<<ROPE_BLOCKS + (T_ / 32) * (HD_ / 32) * B_ * NKV_, 256, 0, stream>>>(
      qkv, Kb, Vt);

  // 4. causal flash attention: v9, 8-wave blocks (4 waves/SIMD), 512 blocks
  flash_attn<<<B_ * NH_ * (T_ / 128), 512, 0, stream>>>(qkv, Kb, Vt, attn_o);

  // 5. output projection: (4096,2048) x (2048,2048) -> fp32
  gemm_bt<float><<<(MROWS / 128) * (D_ / 128), 256, 0, stream>>>(
      attn_o, wo_t, out, MROWS, D_, D_);
}